// Round 6
// baseline (18331.102 us; speedup 1.0000x reference)
//
#include <hip/hip_runtime.h>
#include <cstdint>
#include <cstddef>

#define B_    64
#define NP1   1025
#define N_    1024
#define D_    256
#define DP1   257
#define L_    4
#define H_    4
#define MT    1024   // ZbT row length (m dim); m=1024 (masked key) excluded
#define NCHE  32     // 32 chunks x 32 m = 1024
#define IPAD  272
#define TR_   1024   // T rows per (b,h): n=0..1023 (row 1024 handled in k_post)

typedef __bf16 bf16;
typedef bf16 bf16x4 __attribute__((ext_vector_type(4)));
typedef bf16 bf16x8 __attribute__((ext_vector_type(8)));
typedef float f32x4 __attribute__((ext_vector_type(4)));

__device__ __forceinline__ f32x4 mfma16(bf16x8 a, bf16x8 b, f32x4 c) {
    return __builtin_amdgcn_mfma_f32_16x16x32_bf16(a, b, c, 0, 0, 0);
}

__device__ __forceinline__ void async16(const void* g, void* l) {
    __builtin_amdgcn_global_load_lds(
        (const __attribute__((address_space(1))) void*)g,
        (__attribute__((address_space(3))) void*)l, 16, 0, 0);
}

// ---------------------------------------------------------------------------
__global__ void k_prep_pq(const float* __restrict__ ap,
                          bf16* __restrict__ Pb, bf16* __restrict__ Qt) {
    int idx = blockIdx.x * 256 + threadIdx.x;   // L*H*D*D = 1048576
    int j  = idx & 255;
    int i  = (idx >> 8) & 255;
    int lh = idx >> 16;
    const float* base = ap + (size_t)lh * 2 * D_ * D_;
    float p = base[i * D_ + j];
    float q = base[D_ * D_ + i * D_ + j];
    Pb[((size_t)lh * D_ + i) * D_ + j] = (bf16)p;
    Qt[((size_t)lh * D_ + j) * D_ + i] = (bf16)q;   // Qt[j][i] = Q[i][j]
}

// ---------------------------------------------------------------------------
// Fused: Zb[b][m][j] = Z[b][m][j] (j<256) and ZbT[b][j][m] = Z[b][m][j]
// (j<257), m<1024. Z read once.
// ---------------------------------------------------------------------------
__global__ __launch_bounds__(256) void k_zbt(const float* __restrict__ Z,
                                             bf16* __restrict__ Zb,
                                             bf16* __restrict__ ZbT) {
    __shared__ float t[64][65];
    int m0 = blockIdx.x * 64, j0 = blockIdx.y * 64, b = blockIdx.z;
    int c = threadIdx.x & 63, r0 = threadIdx.x >> 6;
#pragma unroll
    for (int s = 0; s < 16; s++) {
        int r = s * 4 + r0;
        int j = j0 + c;
        float v = (j < DP1) ? Z[((size_t)b * NP1 + m0 + r) * DP1 + j] : 0.f;
        t[r][c] = v;
        if (j < D_) Zb[((size_t)b * N_ + m0 + r) * D_ + j] = (bf16)v;
    }
    __syncthreads();
#pragma unroll
    for (int s = 0; s < 16; s++) {
        int rr = s * 4 + r0;
        int j = j0 + rr;
        if (j < DP1)
            ZbT[((size_t)b * DP1 + j) * MT + m0 + c] = (bf16)t[c][rr];
    }
}

// ---------------------------------------------------------------------------
// Fused attention, T-form, 16-wave (1024-thread) blocks:
// T[n,j] = sum_{m<1024} relu(ZQ.Z^T)[n,m]*Z[m,j].
// Block = 512 n-rows (32/wave) x ONE head-pair; 16 waves share each staged
// chunk (2x amortization vs round 5) and each block stages the tile for 2
// heads instead of 4 (another 2x). 4 waves/SIMD resident (VGPR=128, LDS
// 106 KB) absorb the barrier-convoy slack. Counted-vmcnt raw-barrier
// pipeline + serpentine head walk identical to the verified round-5 kernel.
// Grid 256 = 64 b x 2 ng x 2 hp = one dispatch round, XCD-swizzled.
// ---------------------------------------------------------------------------
__global__ __launch_bounds__(1024, 1) void k_attn(const bf16* __restrict__ Zb,
                                                  const bf16* __restrict__ ZbT,
                                                  const bf16* __restrict__ Qt,
                                                  bf16* __restrict__ T,
                                                  bf16* __restrict__ Tlab,
                                                  int layer) {
    __shared__ bf16 zbS[2][32][256];   // XOR-swizzled: f(r) = r&7
    __shared__ bf16 ztS[2][IPAD][32];  // f(r) = (r>>1)&3
    __shared__ bf16 sl[16][32][40];    // per-wave roundtrip scratch

    const int tid  = threadIdx.x;
    const int id   = blockIdx.x;
    const int wave = tid >> 6, lane = tid & 63;
    const int quad = lane >> 4, l16 = lane & 15;

    // id -> (xcd, b, ng, hp): 32 blocks per XCD = 8 b x 2 ng x 2 hp
    const int xcd = id & 7, u = id >> 3;
    const int b   = xcd + 8 * (u & 7);
    const int ng  = (u >> 3) & 1;
    const int hp  = u >> 4;             // 0..1
    const int n0w = ng * 512 + wave * 32;

    const bf16* Zbb  = Zb  + (size_t)b * N_ * D_;
    const bf16* ZbTb = ZbT + (size_t)b * DP1 * MT;

    const int zrow  = wave * 2 + (lane >> 5);          // 0..31
    const int zscol = ((lane & 31) ^ (zrow & 7)) * 8;
    const int krow  = wave * 16 + (lane >> 2);         // 0..255
    const int kscol = ((lane & 3) ^ ((lane >> 3) & 3)) * 8;
    const int xs    = l16 & 7;
    const int kf    = (l16 >> 1) & 3;

    auto stage = [&](int mc_, int p_) {
        int m0 = mc_ * 32;
        const bf16* zsrc = Zbb + (size_t)(m0 + zrow) * D_ + zscol;
        async16(zsrc, &zbS[p_][wave * 2][0]);
        const bf16* ksrc = ZbTb + (size_t)krow * MT + m0 + kscol;
        async16(ksrc, &ztS[p_][wave * 16][0]);
        if (wave == 0)
            async16(ksrc + (size_t)256 * MT, &ztS[p_][256][0]);
    };

    int p = 0;   // current LDS buffer parity (tracked across heads for reuse)

    for (int h2 = 0; h2 < 2; h2++) {
        const int h = hp * 2 + h2;
        const bf16* Qth = Qt + (size_t)(layer * H_ + h) * D_ * D_;

        if (h2 == 0) stage(0, 0);   // overlap first-chunk fill with ZQ phase

        f32x4 acc[2][17];
#pragma unroll
        for (int ns = 0; ns < 2; ns++)
#pragma unroll
            for (int it = 0; it < 17; it++) acc[ns][it] = (f32x4){0.f, 0.f, 0.f, 0.f};

        // ---- phase 1: ZQ^T -> zqa frags (b64-packed roundtrip) ----
        bf16x8 zqa[2][8];
#pragma unroll 2
        for (int jc = 0; jc < 8; jc++) {
            f32x4 c00 = (f32x4){0.f,0.f,0.f,0.f}, c01 = c00, c10 = c00, c11 = c00;
#pragma unroll
            for (int kc = 0; kc < 8; kc++) {
                const bf16* qb = Qth + (size_t)(jc * 32 + l16) * D_ + kc * 32 + quad * 8;
                const bf16* az = Zbb + (size_t)(n0w + l16) * D_ + kc * 32 + quad * 8;
                bf16x8 q0 = *(const bf16x8*)(qb);
                bf16x8 q1 = *(const bf16x8*)(qb + 16 * D_);
                bf16x8 a0 = *(const bf16x8*)(az);
                bf16x8 a1 = *(const bf16x8*)(az + 16 * D_);
                c00 = mfma16(q0, a0, c00);
                c01 = mfma16(q0, a1, c01);
                c10 = mfma16(q1, a0, c10);
                c11 = mfma16(q1, a1, c11);
            }
            f32x4 cv[2][2] = {{c00, c01}, {c10, c11}};
#pragma unroll
            for (int jt = 0; jt < 2; jt++)
#pragma unroll
                for (int ns = 0; ns < 2; ns++) {
                    bf16x4 pk;
#pragma unroll
                    for (int r = 0; r < 4; r++) pk[r] = (bf16)cv[jt][ns][r];
                    *(bf16x4*)(&sl[wave][ns * 16 + l16][jt * 16 + quad * 4]) = pk;
                }
#pragma unroll
            for (int ns = 0; ns < 2; ns++)
                zqa[ns][jc] = *(const bf16x8*)(&sl[wave][ns * 16 + l16][quad * 8]);
        }

        if (h2 == 0) {
            // chunk 0 must be resident before the pipeline starts
            asm volatile("s_waitcnt vmcnt(0)" ::: "memory");
            __builtin_amdgcn_s_barrier();
            __builtin_amdgcn_sched_barrier(0);
        }
        // h2=1: buffer p already holds this head's first chunk
        // (serpentine reuse: head h2=1 starts where h2=0 ended).

        for (int cc = 0; cc < NCHE; cc++) {
            const bool haveNext = (cc + 1 < NCHE);
            if (haveNext) {
                int mcn = (h2 & 1) ? (NCHE - 2 - cc) : (cc + 1);
                stage(mcn, p ^ 1);
                // wait own current-chunk loads; leave next-chunk (2/3) in flight
                if (wave == 0) asm volatile("s_waitcnt vmcnt(3)" ::: "memory");
                else           asm volatile("s_waitcnt vmcnt(2)" ::: "memory");
            } else {
                asm volatile("s_waitcnt vmcnt(0)" ::: "memory");
            }
            __builtin_amdgcn_s_barrier();        // all waves' chunk-cc loads landed
            __builtin_amdgcn_sched_barrier(0);

            // ---- S^T = relu(Zb_chunk . ZQ^T), b64-packed roundtrip ----
#pragma unroll
            for (int mt = 0; mt < 2; mt++) {
                f32x4 st0 = (f32x4){0.f,0.f,0.f,0.f}, st1 = st0;
                const bf16* zr = &zbS[p][mt * 16 + l16][0];
                __builtin_amdgcn_s_setprio(1);
#pragma unroll
                for (int kc = 0; kc < 8; kc++) {
                    bf16x8 az = *(const bf16x8*)(zr + (((kc * 4 + quad) ^ xs) * 8));
                    st0 = mfma16(az, zqa[0][kc], st0);
                    st1 = mfma16(az, zqa[1][kc], st1);
                }
                __builtin_amdgcn_s_setprio(0);
                bf16x4 p0, p1;
#pragma unroll
                for (int r = 0; r < 4; r++) {
                    p0[r] = (bf16)(st0[r] > 0.f ? st0[r] : 0.f);
                    p1[r] = (bf16)(st1[r] > 0.f ? st1[r] : 0.f);
                }
                *(bf16x4*)(&sl[wave][l16][mt * 16 + quad * 4])      = p0;
                *(bf16x4*)(&sl[wave][16 + l16][mt * 16 + quad * 4]) = p1;
            }
            bf16x8 sfrag[2];
#pragma unroll
            for (int ns = 0; ns < 2; ns++)
                sfrag[ns] = *(const bf16x8*)(&sl[wave][ns * 16 + l16][quad * 8]);

            // ---- acc(T) += S . ZbT_chunk^T ----
            __builtin_amdgcn_s_setprio(1);
#pragma unroll
            for (int it = 0; it < 17; it++) {
                const bf16* kr = &ztS[p][it * 16 + l16][0];
                bf16x8 bk = *(const bf16x8*)(kr + ((quad ^ kf) * 8));
                acc[0][it] = mfma16(sfrag[0], bk, acc[0][it]);
                acc[1][it] = mfma16(sfrag[1], bk, acc[1][it]);
            }
            __builtin_amdgcn_s_setprio(0);

            __builtin_amdgcn_sched_barrier(0);
            __builtin_amdgcn_s_barrier();        // all waves done reading buf p
            if (haveNext) p ^= 1;
        }

        // ---- per-head epilogue: write T (bf16); j=256 goes to Tlab ----
        bf16* Th  = T    + (size_t)(b * H_ + h) * TR_ * D_;
        bf16* Tlh = Tlab + (size_t)(b * H_ + h) * TR_;
#pragma unroll
        for (int ns = 0; ns < 2; ns++)
#pragma unroll
            for (int it = 0; it < 17; it++)
#pragma unroll
                for (int r = 0; r < 4; r++) {
                    int n = n0w + ns * 16 + quad * 4 + r;   // < 1024
                    float v = acc[ns][it][r];
                    if (it < 16)
                        Th[(size_t)n * D_ + it * 16 + l16] = (bf16)v;
                    else if (l16 == 0)
                        Tlh[n] = (bf16)v;
                }
    }
}

// ---------------------------------------------------------------------------
// Z[b,n,i] += (1/N) * sum_h T_h[n,:] . P_h[i,:]   (i<256), plus label column
// i=256 from Tlab. Blocks 512..575: scalar path for query row n=1024,
// INCLUDING the P contraction (res = T_row . P^T, label passes through).
// ---------------------------------------------------------------------------
__global__ __launch_bounds__(256, 2) void k_post(const bf16* __restrict__ T,
                                                 const bf16* __restrict__ Tlab,
                                                 const bf16* __restrict__ Pb,
                                                 const bf16* __restrict__ Zb,
                                                 const bf16* __restrict__ ZbT,
                                                 const bf16* __restrict__ Qt,
                                                 float* __restrict__ Z, int layer) {
    __shared__ float lz1[256];
    __shared__ float lzq[256];
    __shared__ float lsS[1024];
    __shared__ float lT[256];
    __shared__ float llab[256];

    const int tid  = threadIdx.x;
    const int id   = blockIdx.x;

    if (id >= 512) {
        // ---- query row n = 1024 (one block per b), scalar GEMV chain ----
        const int b = id - 512;
        const bf16* Zbb  = Zb  + (size_t)b * N_ * D_;
        const bf16* tr   = ZbT + ((size_t)b * DP1 + tid) * MT;  // row j=tid
        const bf16* zlab = ZbT + ((size_t)b * DP1 + D_) * MT;   // row j=256
        lz1[tid] = Z[((size_t)b * NP1 + N_) * DP1 + tid];
        float outacc = 0.f, labacc = 0.f;
        __syncthreads();
        for (int h = 0; h < H_; h++) {
            const bf16* Qth = Qt + (size_t)(layer * H_ + h) * D_ * D_;
            const bf16* Ph  = Pb + (size_t)(layer * H_ + h) * D_ * D_;
            {   // zq[j] = sum_i z1[i] Q[i][j] ; Qt[j][i] contiguous
                float a = 0.f;
                const bf16* qr = Qth + (size_t)tid * D_;
                for (int i8 = 0; i8 < 32; i8++) {
                    bf16x8 q = *(const bf16x8*)(qr + i8 * 8);
#pragma unroll
                    for (int k = 0; k < 8; k++) a += lz1[i8 * 8 + k] * (float)q[k];
                }
                lzq[tid] = a;
            }
            __syncthreads();
            for (int m = tid; m < N_; m += 256) {
                float a = 0.f;
                const bf16* zr = Zbb + (size_t)m * D_;
                for (int j8 = 0; j8 < 32; j8++) {
                    bf16x8 z8 = *(const bf16x8*)(zr + j8 * 8);
#pragma unroll
                    for (int k = 0; k < 8; k++) a += lzq[j8 * 8 + k] * (float)z8[k];
                }
                lsS[m] = a > 0.f ? a : 0.f;
            }
            __syncthreads();
            {   // T-row: lT[j=tid] = sum_m S[m] * Z[m,j]  (ZbT row contiguous)
                float tv = 0.f;
                for (int m8 = 0; m8 < 128; m8++) {
                    bf16x8 t8 = *(const bf16x8*)(tr + m8 * 8);
#pragma unroll
                    for (int k = 0; k < 8; k++) tv += lsS[m8 * 8 + k] * (float)t8[k];
                }
                lT[tid] = tv;
            }
            for (int m = tid; m < N_; m += 256)
                labacc += lsS[m] * (float)zlab[m];
            __syncthreads();
            {   // P contraction: outacc += sum_j lT[j] * P[i=tid][j]
                const bf16* pr = Ph + (size_t)tid * D_;
                for (int j8 = 0; j8 < 32; j8++) {
                    bf16x8 p8 = *(const bf16x8*)(pr + j8 * 8);
#pragma unroll
                    for (int k = 0; k < 8; k++) outacc += lT[j8 * 8 + k] * (float)p8[k];
                }
            }
            __syncthreads();   // protect lzq/lsS/lT before next head
        }
        const float inv = 1.0f / (float)N_;
        Z[((size_t)b * NP1 + N_) * DP1 + tid] += outacc * inv;
        llab[tid] = labacc;
        __syncthreads();
        if (tid == 0) {
            float s = 0.f;
            for (int t = 0; t < 256; t++) s += llab[t];
            Z[((size_t)b * NP1 + N_) * DP1 + D_] += s * inv;
        }
        return;
    }

    const int wave = tid >> 6, lane = tid & 63;
    const int quad = lane >> 4, l16 = lane & 15;
    const int xcd = id & 7, u = id >> 3;
    const int b   = xcd + 8 * (u & 3) + 32 * (u >> 5);
    const int bx  = (u >> 2) & 7;
    const int n0w = bx * 128 + wave * 32;

    f32x4 acc[2][16];
#pragma unroll
    for (int ns = 0; ns < 2; ns++)
#pragma unroll
        for (int it = 0; it < 16; it++) acc[ns][it] = (f32x4){0.f, 0.f, 0.f, 0.f};

    for (int h = 0; h < H_; h++) {
        const bf16* Th = T  + (size_t)(b * H_ + h) * TR_ * D_;
        const bf16* Ph = Pb + (size_t)(layer * H_ + h) * D_ * D_;
#pragma unroll 2
        for (int kc = 0; kc < 8; kc++) {
            bf16x8 af[2];
#pragma unroll
            for (int ns = 0; ns < 2; ns++) {
                int row = n0w + ns * 16 + l16;   // < 1024
                af[ns] = *(const bf16x8*)(Th + (size_t)row * D_ + kc * 32 + quad * 8);
            }
#pragma unroll
            for (int it = 0; it < 16; it++) {
                bf16x8 bp = *(const bf16x8*)(Ph + (size_t)(it * 16 + l16) * D_ + kc * 32 + quad * 8);
                acc[0][it] = mfma16(af[0], bp, acc[0][it]);
                acc[1][it] = mfma16(af[1], bp, acc[1][it]);
            }
        }
    }

    const float inv = 1.0f / (float)N_;
#pragma unroll
    for (int ns = 0; ns < 2; ns++)
#pragma unroll
        for (int it = 0; it < 16; it++)
#pragma unroll
            for (int r = 0; r < 4; r++) {
                int n = n0w + ns * 16 + quad * 4 + r;   // < 1024
                int i = it * 16 + l16;                   // < 256
                Z[((size_t)b * NP1 + n) * DP1 + i] += acc[ns][it][r] * inv;
            }
    // label column i = 256
    if (tid < 128) {
        int n = bx * 128 + tid;
        float s = 0.f;
#pragma unroll
        for (int h = 0; h < H_; h++)
            s += (float)Tlab[(size_t)(b * H_ + h) * TR_ + n];
        Z[((size_t)b * NP1 + n) * DP1 + D_] += s * inv;
    }
}

// ---------------------------------------------------------------------------
extern "C" void kernel_launch(void* const* d_in, const int* in_sizes, int n_in,
                              void* d_out, int out_size, void* d_ws, size_t ws_size,
                              hipStream_t stream) {
    const float* Zin = (const float*)d_in[0];
    const float* ap  = (const float*)d_in[1];
    float* Z = (float*)d_out;

    char* ws = (char*)d_ws;
    const size_t sz_Zb  = (size_t)B_ * N_ * D_ * sizeof(bf16);          // 33.6 MB
    const size_t sz_ZbT = (size_t)B_ * DP1 * MT * sizeof(bf16);         // 33.7 MB
    const size_t sz_T   = (size_t)B_ * H_ * TR_ * D_ * sizeof(bf16);    // 134.2 MB
    const size_t sz_Tl  = (size_t)B_ * H_ * TR_ * sizeof(bf16);         // 0.5 MB
    const size_t sz_P   = (size_t)L_ * H_ * D_ * D_ * sizeof(bf16);     // 2 MB
    bf16* Zb  = (bf16*)ws;
    bf16* ZbT = (bf16*)(ws + sz_Zb);
    bf16* Tb  = (bf16*)(ws + sz_Zb + sz_ZbT);
    bf16* Tl  = (bf16*)(ws + sz_Zb + sz_ZbT + sz_T);
    bf16* Pb  = (bf16*)(ws + sz_Zb + sz_ZbT + sz_T + sz_Tl);
    bf16* Qt  = (bf16*)(ws + sz_Zb + sz_ZbT + sz_T + sz_Tl + sz_P);

    hipMemcpyAsync(Z, Zin, (size_t)B_ * NP1 * DP1 * sizeof(float),
                   hipMemcpyDeviceToDevice, stream);

    k_prep_pq<<<dim3((L_ * H_ * D_ * D_) / 256), 256, 0, stream>>>(ap, Pb, Qt);

    for (int l = 0; l < L_; l++) {
        k_zbt<<<dim3(N_ / 64, 5, B_), 256, 0, stream>>>(Z, Zb, ZbT);
        k_attn<<<dim3(256), 1024, 0, stream>>>(Zb, ZbT, Qt, Tb, Tl, l);
        k_post<<<dim3(576), 256, 0, stream>>>(Tb, Tl, Pb, Zb, ZbT, Qt, Z, l);
    }
}

// Round 7
// 3589.887 us; speedup vs baseline: 5.1063x; 5.1063x over previous
//
#include <hip/hip_runtime.h>
#include <cstdint>
#include <cstddef>

#define B_    64
#define NP1   1025
#define N_    1024
#define D_    256
#define DP1   257
#define L_    4
#define H_    4
#define MT    1024   // ZbT row length (m dim); m=1024 (masked key) excluded
#define NCHE  32     // 32 chunks x 32 m = 1024
#define IPAD  272
#define TR_   1024   // T rows per (b,h): n=0..1023 (row 1024 handled in k_attn special)

typedef __bf16 bf16;
typedef bf16 bf16x4 __attribute__((ext_vector_type(4)));
typedef bf16 bf16x8 __attribute__((ext_vector_type(8)));
typedef float f32x4 __attribute__((ext_vector_type(4)));

__device__ __forceinline__ f32x4 mfma16(bf16x8 a, bf16x8 b, f32x4 c) {
    return __builtin_amdgcn_mfma_f32_16x16x32_bf16(a, b, c, 0, 0, 0);
}

__device__ __forceinline__ void async16(const void* g, void* l) {
    __builtin_amdgcn_global_load_lds(
        (const __attribute__((address_space(1))) void*)g,
        (__attribute__((address_space(3))) void*)l, 16, 0, 0);
}

// ---------------------------------------------------------------------------
__global__ void k_prep_pq(const float* __restrict__ ap,
                          bf16* __restrict__ Pb, bf16* __restrict__ Qt) {
    int idx = blockIdx.x * 256 + threadIdx.x;   // L*H*D*D = 1048576
    int j  = idx & 255;
    int i  = (idx >> 8) & 255;
    int lh = idx >> 16;
    const float* base = ap + (size_t)lh * 2 * D_ * D_;
    float p = base[i * D_ + j];
    float q = base[D_ * D_ + i * D_ + j];
    Pb[((size_t)lh * D_ + i) * D_ + j] = (bf16)p;
    Qt[((size_t)lh * D_ + j) * D_ + i] = (bf16)q;   // Qt[j][i] = Q[i][j]
}

// ---------------------------------------------------------------------------
// One-time (layer 0) staging: Zb[b][m][j] (j<256) and ZbT[b][j][m] (j<257),
// m<1024. Subsequent layers' Zb/ZbT are produced by k_post.
// ---------------------------------------------------------------------------
__global__ __launch_bounds__(256) void k_zbt(const float* __restrict__ Z,
                                             bf16* __restrict__ Zb,
                                             bf16* __restrict__ ZbT) {
    __shared__ float t[64][65];
    int m0 = blockIdx.x * 64, j0 = blockIdx.y * 64, b = blockIdx.z;
    int c = threadIdx.x & 63, r0 = threadIdx.x >> 6;
#pragma unroll
    for (int s = 0; s < 16; s++) {
        int r = s * 4 + r0;
        int j = j0 + c;
        float v = (j < DP1) ? Z[((size_t)b * NP1 + m0 + r) * DP1 + j] : 0.f;
        t[r][c] = v;
        if (j < D_) Zb[((size_t)b * N_ + m0 + r) * D_ + j] = (bf16)v;
    }
    __syncthreads();
#pragma unroll
    for (int s = 0; s < 16; s++) {
        int rr = s * 4 + r0;
        int j = j0 + rr;
        if (j < DP1)
            ZbT[((size_t)b * DP1 + j) * MT + m0 + c] = (bf16)t[c][rr];
    }
}

// ---------------------------------------------------------------------------
// Fused attention, T-form, 8-wave blocks (round-5 verified structure):
// counted-vmcnt raw-barrier pipeline + serpentine head passes.
// ids 0..255: main blocks (256 n-rows x 4 heads, write T/Tlab).
// ids 256..319: query-row n=1024 GEMV chain (reads layer-l Zb/ZbT/Qt/Pb,
// updates Z row 1024 directly) — moved here from k_post so k_post may
// overwrite Zb/ZbT with next-layer values without a race.
// ---------------------------------------------------------------------------
__global__ __launch_bounds__(512, 1) void k_attn(const bf16* __restrict__ Zb,
                                                 const bf16* __restrict__ ZbT,
                                                 const bf16* __restrict__ Qt,
                                                 const bf16* __restrict__ Pb,
                                                 float* __restrict__ Z,
                                                 bf16* __restrict__ T,
                                                 bf16* __restrict__ Tlab,
                                                 int layer) {
    __shared__ bf16 zbS[2][32][256];   // XOR-swizzled: f(r) = r&7
    __shared__ bf16 ztS[2][IPAD][32];  // f(r) = (r>>1)&3
    __shared__ bf16 sl[8][32][40];     // per-wave roundtrip scratch

    const int tid  = threadIdx.x;
    const int id   = blockIdx.x;
    const int wave = tid >> 6, lane = tid & 63;
    const int quad = lane >> 4, l16 = lane & 15;

    if (id >= 256) {
        // ---- query row n = 1024 (one block per b), scalar GEMV chain ----
        const int bq = id - 256;
        float* lz1 = (float*)&zbS[0][0][0];   // 256
        float* lzq = lz1 + 256;               // 256
        float* lsS = lzq + 256;               // 1024
        float* lT  = lsS + 1024;              // 257
        const bf16* Zbb2  = Zb  + (size_t)bq * N_ * D_;
        const bf16* ZbTb2 = ZbT + (size_t)bq * DP1 * MT;
        if (tid < 256) lz1[tid] = Z[((size_t)bq * NP1 + N_) * DP1 + tid];
        float outacc = 0.f, labacc = 0.f;
        __syncthreads();
        for (int h = 0; h < H_; h++) {
            const bf16* Qth = Qt + (size_t)(layer * H_ + h) * D_ * D_;
            const bf16* Ph  = Pb + (size_t)(layer * H_ + h) * D_ * D_;
            if (tid < 256) {   // zq[j] = sum_i z1[i] Q[i][j]
                float a = 0.f;
                const bf16* qr = Qth + (size_t)tid * D_;
                for (int i8 = 0; i8 < 32; i8++) {
                    bf16x8 q = *(const bf16x8*)(qr + i8 * 8);
#pragma unroll
                    for (int k = 0; k < 8; k++) a += lz1[i8 * 8 + k] * (float)q[k];
                }
                lzq[tid] = a;
            }
            __syncthreads();
            for (int m = tid; m < N_; m += 512) {
                float a = 0.f;
                const bf16* zr = Zbb2 + (size_t)m * D_;
                for (int j8 = 0; j8 < 32; j8++) {
                    bf16x8 z8 = *(const bf16x8*)(zr + j8 * 8);
#pragma unroll
                    for (int k = 0; k < 8; k++) a += lzq[j8 * 8 + k] * (float)z8[k];
                }
                lsS[m] = a > 0.f ? a : 0.f;
            }
            __syncthreads();
            if (tid < DP1) {   // lT[j] = sum_m S[m] * Z[m,j]
                float tv = 0.f;
                const bf16* tr2 = ZbTb2 + (size_t)tid * MT;
                for (int m8 = 0; m8 < 128; m8++) {
                    bf16x8 t8 = *(const bf16x8*)(tr2 + m8 * 8);
#pragma unroll
                    for (int k = 0; k < 8; k++) tv += lsS[m8 * 8 + k] * (float)t8[k];
                }
                lT[tid] = tv;
            }
            __syncthreads();
            if (tid < 256) {   // P contraction
                const bf16* pr = Ph + (size_t)tid * D_;
                for (int j8 = 0; j8 < 32; j8++) {
                    bf16x8 p8 = *(const bf16x8*)(pr + j8 * 8);
#pragma unroll
                    for (int k = 0; k < 8; k++) outacc += lT[j8 * 8 + k] * (float)p8[k];
                }
            } else if (tid == 256) {
                labacc += lT[256];   // Pf[256][j] = delta(j==256)
            }
            __syncthreads();   // protect lzq/lsS/lT before next head
        }
        const float inv = 1.0f / (float)N_;
        if (tid < 256)  Z[((size_t)bq * NP1 + N_) * DP1 + tid] += outacc * inv;
        if (tid == 256) Z[((size_t)bq * NP1 + N_) * DP1 + D_]  += labacc * inv;
        return;
    }

    // bijective XCD mapping: 32 blocks per XCD = 8 b x 4 n-blocks
    const int xcd = id & 7, u = id >> 3;
    const int b   = xcd + 8 * (u & 7);
    const int bx  = u >> 3;             // 0..3
    const int n0w = bx * 256 + wave * 32;

    const bf16* Zbb  = Zb  + (size_t)b * N_ * D_;
    const bf16* ZbTb = ZbT + (size_t)b * DP1 * MT;

    const int zrow  = wave * 2 + (lane >> 5);          // 0..15
    const int zscol = ((lane & 31) ^ (zrow & 7)) * 8;
    const int krow  = wave * 16 + (lane >> 2);         // 0..127
    const int kscol = ((lane & 3) ^ ((lane >> 3) & 3)) * 8;
    const int xs    = l16 & 7;
    const int kf    = (l16 >> 1) & 3;

    auto stage = [&](int mc_, int p_) {
        int m0 = mc_ * 32;
        const bf16* zsrc = Zbb + (size_t)(m0 + zrow) * D_ + zscol;
#pragma unroll
        for (int t = 0; t < 2; t++)
            async16(zsrc + (size_t)t * 16 * D_, &zbS[p_][t * 16 + wave * 2][0]);
        const bf16* ksrc = ZbTb + (size_t)krow * MT + m0 + kscol;
#pragma unroll
        for (int t = 0; t < 2; t++)
            async16(ksrc + (size_t)t * 128 * MT, &ztS[p_][t * 128 + wave * 16][0]);
        if (wave == 0)
            async16(ksrc + (size_t)256 * MT, &ztS[p_][256][0]);
    };

    int p = 0;   // current LDS buffer parity (tracked across heads for reuse)

    for (int h = 0; h < H_; h++) {
        const bf16* Qth = Qt + (size_t)(layer * H_ + h) * D_ * D_;

        if (h == 0) stage(0, 0);   // overlap first-chunk fill with ZQ phase

        f32x4 acc[2][17];
#pragma unroll
        for (int ns = 0; ns < 2; ns++)
#pragma unroll
            for (int it = 0; it < 17; it++) acc[ns][it] = (f32x4){0.f, 0.f, 0.f, 0.f};

        // ---- phase 1: ZQ^T -> zqa frags (b64-packed roundtrip) ----
        bf16x8 zqa[2][8];
#pragma unroll 2
        for (int jc = 0; jc < 8; jc++) {
            f32x4 c00 = (f32x4){0.f,0.f,0.f,0.f}, c01 = c00, c10 = c00, c11 = c00;
#pragma unroll
            for (int kc = 0; kc < 8; kc++) {
                const bf16* qb = Qth + (size_t)(jc * 32 + l16) * D_ + kc * 32 + quad * 8;
                const bf16* az = Zbb + (size_t)(n0w + l16) * D_ + kc * 32 + quad * 8;
                bf16x8 q0 = *(const bf16x8*)(qb);
                bf16x8 q1 = *(const bf16x8*)(qb + 16 * D_);
                bf16x8 a0 = *(const bf16x8*)(az);
                bf16x8 a1 = *(const bf16x8*)(az + 16 * D_);
                c00 = mfma16(q0, a0, c00);
                c01 = mfma16(q0, a1, c01);
                c10 = mfma16(q1, a0, c10);
                c11 = mfma16(q1, a1, c11);
            }
            f32x4 cv[2][2] = {{c00, c01}, {c10, c11}};
#pragma unroll
            for (int jt = 0; jt < 2; jt++)
#pragma unroll
                for (int ns = 0; ns < 2; ns++) {
                    bf16x4 pk;
#pragma unroll
                    for (int r = 0; r < 4; r++) pk[r] = (bf16)cv[jt][ns][r];
                    *(bf16x4*)(&sl[wave][ns * 16 + l16][jt * 16 + quad * 4]) = pk;
                }
#pragma unroll
            for (int ns = 0; ns < 2; ns++)
                zqa[ns][jc] = *(const bf16x8*)(&sl[wave][ns * 16 + l16][quad * 8]);
        }

        if (h == 0) {
            // chunk 0 must be resident before the pipeline starts
            asm volatile("s_waitcnt vmcnt(0)" ::: "memory");
            __builtin_amdgcn_s_barrier();
            __builtin_amdgcn_sched_barrier(0);
        }
        // h>0: current buffer p already holds this head's first chunk
        // (serpentine reuse: head h starts where head h-1 ended).

        for (int cc = 0; cc < NCHE; cc++) {
            const bool haveNext = (cc + 1 < NCHE);
            if (haveNext) {
                int mcn = (h & 1) ? (NCHE - 2 - cc) : (cc + 1);
                stage(mcn, p ^ 1);
                // wait own current-chunk loads; leave next-chunk (4/5) in flight
                if (wave == 0) asm volatile("s_waitcnt vmcnt(5)" ::: "memory");
                else           asm volatile("s_waitcnt vmcnt(4)" ::: "memory");
            } else {
                asm volatile("s_waitcnt vmcnt(0)" ::: "memory");
            }
            __builtin_amdgcn_s_barrier();        // all waves' chunk-cc loads landed
            __builtin_amdgcn_sched_barrier(0);

            // ---- S^T = relu(Zb_chunk . ZQ^T), b64-packed roundtrip ----
#pragma unroll
            for (int mt = 0; mt < 2; mt++) {
                f32x4 st0 = (f32x4){0.f,0.f,0.f,0.f}, st1 = st0;
                const bf16* zr = &zbS[p][mt * 16 + l16][0];
                __builtin_amdgcn_s_setprio(1);
#pragma unroll
                for (int kc = 0; kc < 8; kc++) {
                    bf16x8 az = *(const bf16x8*)(zr + (((kc * 4 + quad) ^ xs) * 8));
                    st0 = mfma16(az, zqa[0][kc], st0);
                    st1 = mfma16(az, zqa[1][kc], st1);
                }
                __builtin_amdgcn_s_setprio(0);
                bf16x4 p0, p1;
#pragma unroll
                for (int r = 0; r < 4; r++) {
                    p0[r] = (bf16)(st0[r] > 0.f ? st0[r] : 0.f);
                    p1[r] = (bf16)(st1[r] > 0.f ? st1[r] : 0.f);
                }
                *(bf16x4*)(&sl[wave][l16][mt * 16 + quad * 4])      = p0;
                *(bf16x4*)(&sl[wave][16 + l16][mt * 16 + quad * 4]) = p1;
            }
            bf16x8 sfrag[2];
#pragma unroll
            for (int ns = 0; ns < 2; ns++)
                sfrag[ns] = *(const bf16x8*)(&sl[wave][ns * 16 + l16][quad * 8]);

            // ---- acc(T) += S . ZbT_chunk^T ----
            __builtin_amdgcn_s_setprio(1);
#pragma unroll
            for (int it = 0; it < 17; it++) {
                const bf16* kr = &ztS[p][it * 16 + l16][0];
                bf16x8 bk = *(const bf16x8*)(kr + ((quad ^ kf) * 8));
                acc[0][it] = mfma16(sfrag[0], bk, acc[0][it]);
                acc[1][it] = mfma16(sfrag[1], bk, acc[1][it]);
            }
            __builtin_amdgcn_s_setprio(0);

            __builtin_amdgcn_sched_barrier(0);
            __builtin_amdgcn_s_barrier();        // all waves done reading buf p
            if (haveNext) p ^= 1;
        }

        // ---- per-head epilogue: write T (bf16); j=256 goes to Tlab ----
        bf16* Th  = T    + (size_t)(b * H_ + h) * TR_ * D_;
        bf16* Tlh = Tlab + (size_t)(b * H_ + h) * TR_;
#pragma unroll
        for (int ns = 0; ns < 2; ns++)
#pragma unroll
            for (int it = 0; it < 17; it++)
#pragma unroll
                for (int r = 0; r < 4; r++) {
                    int n = n0w + ns * 16 + quad * 4 + r;   // < 1024
                    float v = acc[ns][it][r];
                    if (it < 16)
                        Th[(size_t)n * D_ + it * 16 + l16] = (bf16)v;
                    else if (l16 == 0)
                        Tlh[n] = (bf16)v;
                }
    }
}

// ---------------------------------------------------------------------------
// Z[b,n,i] += (1/N) * sum_h T_h[n,:] . P_h[i,:]  (n<1024), label column i=256
// from Tlab; ALSO emits next layer's Zb (bf16) and ZbT (bf16, transposed)
// from the freshly computed Z values (replaces per-layer k_zbt).
// i-dimension split across 2 blocks (ih) -> acc[2][8] = 64 regs ->
// 4 waves/SIMD occupancy. Grid 1024 = one clean round at 4 blocks/CU.
// ---------------------------------------------------------------------------
__global__ __launch_bounds__(256, 4) void k_post(const bf16* __restrict__ T,
                                                 const bf16* __restrict__ Tlab,
                                                 const bf16* __restrict__ Pb,
                                                 float* __restrict__ Z,
                                                 bf16* __restrict__ Zb,
                                                 bf16* __restrict__ ZbT,
                                                 int layer) {
    const int tid  = threadIdx.x;
    const int id   = blockIdx.x;
    const int wave = tid >> 6, lane = tid & 63;
    const int quad = lane >> 4, l16 = lane & 15;
    const int xcd = id & 7, u = id >> 3;               // u: 0..127
    const int b   = xcd + 8 * (u & 3) + 32 * ((u >> 5) & 1);
    const int bx  = (u >> 2) & 7;
    const int ih  = u >> 6;                            // 0..1 i-half
    const int n0w = bx * 128 + wave * 32;
    const int i0  = ih * 128;

    f32x4 acc[2][8];
#pragma unroll
    for (int ns = 0; ns < 2; ns++)
#pragma unroll
        for (int it = 0; it < 8; it++) acc[ns][it] = (f32x4){0.f, 0.f, 0.f, 0.f};

    for (int h = 0; h < H_; h++) {
        const bf16* Th = T  + (size_t)(b * H_ + h) * TR_ * D_;
        const bf16* Ph = Pb + (size_t)(layer * H_ + h) * D_ * D_;
#pragma unroll 2
        for (int kc = 0; kc < 8; kc++) {
            bf16x8 af[2];
#pragma unroll
            for (int ns = 0; ns < 2; ns++) {
                int row = n0w + ns * 16 + l16;   // < 1024
                af[ns] = *(const bf16x8*)(Th + (size_t)row * D_ + kc * 32 + quad * 8);
            }
#pragma unroll
            for (int it = 0; it < 8; it++) {
                bf16x8 bp = *(const bf16x8*)(Ph + (size_t)(i0 + it * 16 + l16) * D_ + kc * 32 + quad * 8);
                acc[0][it] = mfma16(af[0], bp, acc[0][it]);
                acc[1][it] = mfma16(af[1], bp, acc[1][it]);
            }
        }
    }

    const float inv = 1.0f / (float)N_;
    const bool wnext = (layer < L_ - 1);
#pragma unroll
    for (int ns = 0; ns < 2; ns++)
#pragma unroll
        for (int it = 0; it < 8; it++) {
            const int i = i0 + it * 16 + l16;           // < 256
            const int nbase = n0w + ns * 16 + quad * 4; // < 1024
            bf16x4 zpk;
#pragma unroll
            for (int r = 0; r < 4; r++) {
                int n = nbase + r;
                size_t zi = ((size_t)b * NP1 + n) * DP1 + i;
                float v = Z[zi] + acc[ns][it][r] * inv;
                Z[zi] = v;
                zpk[r] = (bf16)v;
                if (wnext) Zb[((size_t)b * N_ + n) * D_ + i] = (bf16)v;
            }
            if (wnext)
                *(bf16x4*)(&ZbT[((size_t)b * DP1 + i) * MT + nbase]) = zpk;
        }
    // label column i = 256 (only i-half 0 blocks)
    if (ih == 0 && tid < 128) {
        int n = bx * 128 + tid;
        float s = 0.f;
#pragma unroll
        for (int h = 0; h < H_; h++)
            s += (float)Tlab[(size_t)(b * H_ + h) * TR_ + n];
        size_t zi = ((size_t)b * NP1 + n) * DP1 + D_;
        float v = Z[zi] + s * inv;
        Z[zi] = v;
        if (wnext) ZbT[((size_t)b * DP1 + D_) * MT + n] = (bf16)v;
    }
}

// ---------------------------------------------------------------------------
extern "C" void kernel_launch(void* const* d_in, const int* in_sizes, int n_in,
                              void* d_out, int out_size, void* d_ws, size_t ws_size,
                              hipStream_t stream) {
    const float* Zin = (const float*)d_in[0];
    const float* ap  = (const float*)d_in[1];
    float* Z = (float*)d_out;

    char* ws = (char*)d_ws;
    const size_t sz_Zb  = (size_t)B_ * N_ * D_ * sizeof(bf16);          // 33.6 MB
    const size_t sz_ZbT = (size_t)B_ * DP1 * MT * sizeof(bf16);         // 33.7 MB
    const size_t sz_T   = (size_t)B_ * H_ * TR_ * D_ * sizeof(bf16);    // 134.2 MB
    const size_t sz_Tl  = (size_t)B_ * H_ * TR_ * sizeof(bf16);         // 0.5 MB
    const size_t sz_P   = (size_t)L_ * H_ * D_ * D_ * sizeof(bf16);     // 2 MB
    bf16* Zb  = (bf16*)ws;
    bf16* ZbT = (bf16*)(ws + sz_Zb);
    bf16* Tb  = (bf16*)(ws + sz_Zb + sz_ZbT);
    bf16* Tl  = (bf16*)(ws + sz_Zb + sz_ZbT + sz_T);
    bf16* Pb  = (bf16*)(ws + sz_Zb + sz_ZbT + sz_T + sz_Tl);
    bf16* Qt  = (bf16*)(ws + sz_Zb + sz_ZbT + sz_T + sz_Tl + sz_P);

    hipMemcpyAsync(Z, Zin, (size_t)B_ * NP1 * DP1 * sizeof(float),
                   hipMemcpyDeviceToDevice, stream);

    k_prep_pq<<<dim3((L_ * H_ * D_ * D_) / 256), 256, 0, stream>>>(ap, Pb, Qt);
    k_zbt<<<dim3(N_ / 64, 5, B_), 256, 0, stream>>>(Z, Zb, ZbT);   // layer 0 only

    for (int l = 0; l < L_; l++) {
        k_attn<<<dim3(320), 512, 0, stream>>>(Zb, ZbT, Qt, Pb, Z, Tb, Tl, l);
        k_post<<<dim3(1024), 256, 0, stream>>>(Tb, Tl, Pb, Z, Zb, ZbT, l);
    }
}

// Round 8
// 3325.895 us; speedup vs baseline: 5.5116x; 1.0794x over previous
//
#include <hip/hip_runtime.h>
#include <cstdint>
#include <cstddef>

#define B_    64
#define NP1   1025
#define N_    1024
#define D_    256
#define DP1   257
#define L_    4
#define H_    4
#define MT    1024   // ZbT row length (m dim); m=1024 (masked key) excluded
#define NCHE  32     // 32 chunks x 32 m = 1024
#define IPAD  272
#define TR_   1024   // T rows per (b,h): n=0..1023 (row 1024 handled in k_attn bx==0)

typedef __bf16 bf16;
typedef bf16 bf16x4 __attribute__((ext_vector_type(4)));
typedef bf16 bf16x8 __attribute__((ext_vector_type(8)));
typedef float f32x4 __attribute__((ext_vector_type(4)));

__device__ __forceinline__ f32x4 mfma16(bf16x8 a, bf16x8 b, f32x4 c) {
    return __builtin_amdgcn_mfma_f32_16x16x32_bf16(a, b, c, 0, 0, 0);
}

__device__ __forceinline__ void async16(const void* g, void* l) {
    __builtin_amdgcn_global_load_lds(
        (const __attribute__((address_space(1))) void*)g,
        (__attribute__((address_space(3))) void*)l, 16, 0, 0);
}

// ---------------------------------------------------------------------------
__global__ void k_prep_pq(const float* __restrict__ ap,
                          bf16* __restrict__ Pb, bf16* __restrict__ Qt) {
    int idx = blockIdx.x * 256 + threadIdx.x;   // L*H*D*D = 1048576
    int j  = idx & 255;
    int i  = (idx >> 8) & 255;
    int lh = idx >> 16;
    const float* base = ap + (size_t)lh * 2 * D_ * D_;
    float p = base[i * D_ + j];
    float q = base[D_ * D_ + i * D_ + j];
    Pb[((size_t)lh * D_ + i) * D_ + j] = (bf16)p;
    Qt[((size_t)lh * D_ + j) * D_ + i] = (bf16)q;   // Qt[j][i] = Q[i][j]
}

// ---------------------------------------------------------------------------
// One-time (layer 0) staging: Zb[b][m][j] (j<256) and ZbT[b][j][m] (j<257),
// m<1024. Subsequent layers' Zb/ZbT are produced by k_post.
// ---------------------------------------------------------------------------
__global__ __launch_bounds__(256) void k_zbt(const float* __restrict__ Z,
                                             bf16* __restrict__ Zb,
                                             bf16* __restrict__ ZbT) {
    __shared__ float t[64][65];
    int m0 = blockIdx.x * 64, j0 = blockIdx.y * 64, b = blockIdx.z;
    int c = threadIdx.x & 63, r0 = threadIdx.x >> 6;
#pragma unroll
    for (int s = 0; s < 16; s++) {
        int r = s * 4 + r0;
        int j = j0 + c;
        float v = (j < DP1) ? Z[((size_t)b * NP1 + m0 + r) * DP1 + j] : 0.f;
        t[r][c] = v;
        if (j < D_) Zb[((size_t)b * N_ + m0 + r) * D_ + j] = (bf16)v;
    }
    __syncthreads();
#pragma unroll
    for (int s = 0; s < 16; s++) {
        int rr = s * 4 + r0;
        int j = j0 + rr;
        if (j < DP1)
            ZbT[((size_t)b * DP1 + j) * MT + m0 + c] = (bf16)t[c][rr];
    }
}

// ---------------------------------------------------------------------------
// Fused attention, T-form, 8-wave blocks (round-5 verified structure):
// counted-vmcnt raw-barrier pipeline + serpentine head passes.
// Grid = exactly 256 blocks (one round). Blocks with bx==0 additionally run
// the n=1024 query-row path AFTER their main loop, with all 4 heads fused
// into one sweep over Zb/ZbT (data is L2-hot from the main staging) —
// replaces round-7's 64 extra tail blocks.
// ---------------------------------------------------------------------------
__global__ __launch_bounds__(512, 1) void k_attn(const bf16* __restrict__ Zb,
                                                 const bf16* __restrict__ ZbT,
                                                 const bf16* __restrict__ Qt,
                                                 const bf16* __restrict__ Pb,
                                                 float* __restrict__ Z,
                                                 bf16* __restrict__ T,
                                                 bf16* __restrict__ Tlab,
                                                 int layer) {
    __shared__ bf16 zbS[2][32][256];   // XOR-swizzled: f(r) = r&7
    __shared__ bf16 ztS[2][IPAD][32];  // f(r) = (r>>1)&3
    __shared__ bf16 sl[8][32][40];     // per-wave roundtrip scratch

    const int tid  = threadIdx.x;
    const int id   = blockIdx.x;
    const int wave = tid >> 6, lane = tid & 63;
    const int quad = lane >> 4, l16 = lane & 15;

    // bijective XCD mapping: 32 blocks per XCD = 8 b x 4 n-blocks
    const int xcd = id & 7, u = id >> 3;
    const int b   = xcd + 8 * (u & 7);
    const int bx  = u >> 3;             // 0..3
    const int n0w = bx * 256 + wave * 32;

    const bf16* Zbb  = Zb  + (size_t)b * N_ * D_;
    const bf16* ZbTb = ZbT + (size_t)b * DP1 * MT;

    const int zrow  = wave * 2 + (lane >> 5);          // 0..15
    const int zscol = ((lane & 31) ^ (zrow & 7)) * 8;
    const int krow  = wave * 16 + (lane >> 2);         // 0..127
    const int kscol = ((lane & 3) ^ ((lane >> 3) & 3)) * 8;
    const int xs    = l16 & 7;
    const int kf    = (l16 >> 1) & 3;

    auto stage = [&](int mc_, int p_) {
        int m0 = mc_ * 32;
        const bf16* zsrc = Zbb + (size_t)(m0 + zrow) * D_ + zscol;
#pragma unroll
        for (int t = 0; t < 2; t++)
            async16(zsrc + (size_t)t * 16 * D_, &zbS[p_][t * 16 + wave * 2][0]);
        const bf16* ksrc = ZbTb + (size_t)krow * MT + m0 + kscol;
#pragma unroll
        for (int t = 0; t < 2; t++)
            async16(ksrc + (size_t)t * 128 * MT, &ztS[p_][t * 128 + wave * 16][0]);
        if (wave == 0)
            async16(ksrc + (size_t)256 * MT, &ztS[p_][256][0]);
    };

    int p = 0;   // current LDS buffer parity (tracked across heads for reuse)

    for (int h = 0; h < H_; h++) {
        const bf16* Qth = Qt + (size_t)(layer * H_ + h) * D_ * D_;

        if (h == 0) stage(0, 0);   // overlap first-chunk fill with ZQ phase

        f32x4 acc[2][17];
#pragma unroll
        for (int ns = 0; ns < 2; ns++)
#pragma unroll
            for (int it = 0; it < 17; it++) acc[ns][it] = (f32x4){0.f, 0.f, 0.f, 0.f};

        // ---- phase 1: ZQ^T -> zqa frags (b64-packed roundtrip) ----
        bf16x8 zqa[2][8];
#pragma unroll 2
        for (int jc = 0; jc < 8; jc++) {
            f32x4 c00 = (f32x4){0.f,0.f,0.f,0.f}, c01 = c00, c10 = c00, c11 = c00;
#pragma unroll
            for (int kc = 0; kc < 8; kc++) {
                const bf16* qb = Qth + (size_t)(jc * 32 + l16) * D_ + kc * 32 + quad * 8;
                const bf16* az = Zbb + (size_t)(n0w + l16) * D_ + kc * 32 + quad * 8;
                bf16x8 q0 = *(const bf16x8*)(qb);
                bf16x8 q1 = *(const bf16x8*)(qb + 16 * D_);
                bf16x8 a0 = *(const bf16x8*)(az);
                bf16x8 a1 = *(const bf16x8*)(az + 16 * D_);
                c00 = mfma16(q0, a0, c00);
                c01 = mfma16(q0, a1, c01);
                c10 = mfma16(q1, a0, c10);
                c11 = mfma16(q1, a1, c11);
            }
            f32x4 cv[2][2] = {{c00, c01}, {c10, c11}};
#pragma unroll
            for (int jt = 0; jt < 2; jt++)
#pragma unroll
                for (int ns = 0; ns < 2; ns++) {
                    bf16x4 pk;
#pragma unroll
                    for (int r = 0; r < 4; r++) pk[r] = (bf16)cv[jt][ns][r];
                    *(bf16x4*)(&sl[wave][ns * 16 + l16][jt * 16 + quad * 4]) = pk;
                }
#pragma unroll
            for (int ns = 0; ns < 2; ns++)
                zqa[ns][jc] = *(const bf16x8*)(&sl[wave][ns * 16 + l16][quad * 8]);
        }

        if (h == 0) {
            // chunk 0 must be resident before the pipeline starts
            asm volatile("s_waitcnt vmcnt(0)" ::: "memory");
            __builtin_amdgcn_s_barrier();
            __builtin_amdgcn_sched_barrier(0);
        }
        // h>0: current buffer p already holds this head's first chunk
        // (serpentine reuse: head h starts where head h-1 ended).

        for (int cc = 0; cc < NCHE; cc++) {
            const bool haveNext = (cc + 1 < NCHE);
            if (haveNext) {
                int mcn = (h & 1) ? (NCHE - 2 - cc) : (cc + 1);
                stage(mcn, p ^ 1);
                // wait own current-chunk loads; leave next-chunk (4/5) in flight
                if (wave == 0) asm volatile("s_waitcnt vmcnt(5)" ::: "memory");
                else           asm volatile("s_waitcnt vmcnt(4)" ::: "memory");
            } else {
                asm volatile("s_waitcnt vmcnt(0)" ::: "memory");
            }
            __builtin_amdgcn_s_barrier();        // all waves' chunk-cc loads landed
            __builtin_amdgcn_sched_barrier(0);

            // ---- S^T = relu(Zb_chunk . ZQ^T), b64-packed roundtrip ----
#pragma unroll
            for (int mt = 0; mt < 2; mt++) {
                f32x4 st0 = (f32x4){0.f,0.f,0.f,0.f}, st1 = st0;
                const bf16* zr = &zbS[p][mt * 16 + l16][0];
                __builtin_amdgcn_s_setprio(1);
#pragma unroll
                for (int kc = 0; kc < 8; kc++) {
                    bf16x8 az = *(const bf16x8*)(zr + (((kc * 4 + quad) ^ xs) * 8));
                    st0 = mfma16(az, zqa[0][kc], st0);
                    st1 = mfma16(az, zqa[1][kc], st1);
                }
                __builtin_amdgcn_s_setprio(0);
                bf16x4 p0, p1;
#pragma unroll
                for (int r = 0; r < 4; r++) {
                    p0[r] = (bf16)(st0[r] > 0.f ? st0[r] : 0.f);
                    p1[r] = (bf16)(st1[r] > 0.f ? st1[r] : 0.f);
                }
                *(bf16x4*)(&sl[wave][l16][mt * 16 + quad * 4])      = p0;
                *(bf16x4*)(&sl[wave][16 + l16][mt * 16 + quad * 4]) = p1;
            }
            bf16x8 sfrag[2];
#pragma unroll
            for (int ns = 0; ns < 2; ns++)
                sfrag[ns] = *(const bf16x8*)(&sl[wave][ns * 16 + l16][quad * 8]);

            // ---- acc(T) += S . ZbT_chunk^T ----
            __builtin_amdgcn_s_setprio(1);
#pragma unroll
            for (int it = 0; it < 17; it++) {
                const bf16* kr = &ztS[p][it * 16 + l16][0];
                bf16x8 bk = *(const bf16x8*)(kr + ((quad ^ kf) * 8));
                acc[0][it] = mfma16(sfrag[0], bk, acc[0][it]);
                acc[1][it] = mfma16(sfrag[1], bk, acc[1][it]);
            }
            __builtin_amdgcn_s_setprio(0);

            __builtin_amdgcn_sched_barrier(0);
            __builtin_amdgcn_s_barrier();        // all waves done reading buf p
            if (haveNext) p ^= 1;
        }

        // ---- per-head epilogue: write T (bf16); j=256 goes to Tlab ----
        bf16* Th  = T    + (size_t)(b * H_ + h) * TR_ * D_;
        bf16* Tlh = Tlab + (size_t)(b * H_ + h) * TR_;
#pragma unroll
        for (int ns = 0; ns < 2; ns++)
#pragma unroll
            for (int it = 0; it < 17; it++)
#pragma unroll
                for (int r = 0; r < 4; r++) {
                    int n = n0w + ns * 16 + quad * 4 + r;   // < 1024
                    float v = acc[ns][it][r];
                    if (it < 16)
                        Th[(size_t)n * D_ + it * 16 + l16] = (bf16)v;
                    else if (l16 == 0)
                        Tlh[n] = (bf16)v;
                }
    }

    // ---- n=1024 query row: bx==0 block of each b, all 4 heads fused ----
    if (bx == 0) {
        __syncthreads();   // main loop done in all waves; zbS free for reuse
        float* lz1 = (float*)&zbS[0][0][0];   // 256 f32
        float* lzq = lz1 + 256;               // [4][256]
        float* lsS = lzq + 1024;              // [4][1024]
        float* lT  = lsS + 4096;              // [4][257]   (total 25.6 KB < zbS)
        if (tid < 256) lz1[tid] = Z[((size_t)b * NP1 + N_) * DP1 + tid];
        __syncthreads();
        {   // zq[h][j] = sum_i z1[i] Q_h[i][j]; threads 0..255 do h=0,2; 256..511 h=1,3
            int j = tid & 255, hh = tid >> 8;
            for (int h2 = hh; h2 < H_; h2 += 2) {
                const bf16* qr = Qt + ((size_t)(layer * H_ + h2) * D_ + j) * D_;
                float a = 0.f;
                for (int i8 = 0; i8 < 32; i8++) {
                    bf16x8 q = *(const bf16x8*)(qr + i8 * 8);
#pragma unroll
                    for (int k = 0; k < 8; k++) a += lz1[i8 * 8 + k] * (float)q[k];
                }
                lzq[h2 * 256 + j] = a;
            }
        }
        __syncthreads();
        for (int m = tid; m < N_; m += 512) {   // one Zb sweep, 4 heads
            const bf16* zr = Zbb + (size_t)m * D_;
            float a0 = 0.f, a1 = 0.f, a2 = 0.f, a3 = 0.f;
            for (int j8 = 0; j8 < 32; j8++) {
                bf16x8 z8 = *(const bf16x8*)(zr + j8 * 8);
#pragma unroll
                for (int k = 0; k < 8; k++) {
                    float zv = (float)z8[k];
                    int j = j8 * 8 + k;
                    a0 += lzq[j] * zv;
                    a1 += lzq[256 + j] * zv;
                    a2 += lzq[512 + j] * zv;
                    a3 += lzq[768 + j] * zv;
                }
            }
            lsS[m]        = a0 > 0.f ? a0 : 0.f;
            lsS[1024 + m] = a1 > 0.f ? a1 : 0.f;
            lsS[2048 + m] = a2 > 0.f ? a2 : 0.f;
            lsS[3072 + m] = a3 > 0.f ? a3 : 0.f;
        }
        __syncthreads();
        if (tid < DP1) {   // one ZbT sweep, 4 heads: lT[h][j=tid]
            const bf16* tr2 = ZbTb + (size_t)tid * MT;
            float t0 = 0.f, t1 = 0.f, t2 = 0.f, t3 = 0.f;
            for (int m8 = 0; m8 < 128; m8++) {
                bf16x8 t8 = *(const bf16x8*)(tr2 + m8 * 8);
#pragma unroll
                for (int k = 0; k < 8; k++) {
                    float zv = (float)t8[k];
                    int m = m8 * 8 + k;
                    t0 += lsS[m] * zv;
                    t1 += lsS[1024 + m] * zv;
                    t2 += lsS[2048 + m] * zv;
                    t3 += lsS[3072 + m] * zv;
                }
            }
            lT[tid] = t0; lT[257 + tid] = t1; lT[514 + tid] = t2; lT[771 + tid] = t3;
        }
        __syncthreads();
        const float inv = 1.0f / (float)N_;
        if (tid < 256) {   // P contraction, all 4 heads
            float out = 0.f;
            for (int h2 = 0; h2 < H_; h2++) {
                const bf16* pr = Pb + ((size_t)(layer * H_ + h2) * D_ + tid) * D_;
                for (int j8 = 0; j8 < 32; j8++) {
                    bf16x8 p8 = *(const bf16x8*)(pr + j8 * 8);
#pragma unroll
                    for (int k = 0; k < 8; k++)
                        out += lT[h2 * 257 + j8 * 8 + k] * (float)p8[k];
                }
            }
            Z[((size_t)b * NP1 + N_) * DP1 + tid] += out * inv;
        } else if (tid == 256) {
            float lab = lT[256] + lT[513] + lT[770] + lT[1027];
            Z[((size_t)b * NP1 + N_) * DP1 + D_] += lab * inv;
        }
    }
}

// ---------------------------------------------------------------------------
// Z[b,n,i] += (1/N) * sum_h T_h[n,:] . P_h[i,:]  (n<1024), label column i=256
// from Tlab; ALSO emits next layer's Zb (bf16) and ZbT (bf16, transposed)
// from the freshly computed Z values (replaces per-layer k_zbt).
// i-dimension split across 2 blocks (ih) -> acc[2][8] = 64 regs ->
// 4 waves/SIMD occupancy. Grid 1024 = one clean round at 4 blocks/CU.
// ---------------------------------------------------------------------------
__global__ __launch_bounds__(256, 4) void k_post(const bf16* __restrict__ T,
                                                 const bf16* __restrict__ Tlab,
                                                 const bf16* __restrict__ Pb,
                                                 float* __restrict__ Z,
                                                 bf16* __restrict__ Zb,
                                                 bf16* __restrict__ ZbT,
                                                 int layer) {
    const int tid  = threadIdx.x;
    const int id   = blockIdx.x;
    const int wave = tid >> 6, lane = tid & 63;
    const int quad = lane >> 4, l16 = lane & 15;
    const int xcd = id & 7, u = id >> 3;               // u: 0..127
    const int b   = xcd + 8 * (u & 3) + 32 * ((u >> 5) & 1);
    const int bx  = (u >> 2) & 7;
    const int ih  = u >> 6;                            // 0..1 i-half
    const int n0w = bx * 128 + wave * 32;
    const int i0  = ih * 128;

    f32x4 acc[2][8];
#pragma unroll
    for (int ns = 0; ns < 2; ns++)
#pragma unroll
        for (int it = 0; it < 8; it++) acc[ns][it] = (f32x4){0.f, 0.f, 0.f, 0.f};

    for (int h = 0; h < H_; h++) {
        const bf16* Th = T  + (size_t)(b * H_ + h) * TR_ * D_;
        const bf16* Ph = Pb + (size_t)(layer * H_ + h) * D_ * D_;
#pragma unroll 2
        for (int kc = 0; kc < 8; kc++) {
            bf16x8 af[2];
#pragma unroll
            for (int ns = 0; ns < 2; ns++) {
                int row = n0w + ns * 16 + l16;   // < 1024
                af[ns] = *(const bf16x8*)(Th + (size_t)row * D_ + kc * 32 + quad * 8);
            }
#pragma unroll
            for (int it = 0; it < 8; it++) {
                bf16x8 bp = *(const bf16x8*)(Ph + (size_t)(i0 + it * 16 + l16) * D_ + kc * 32 + quad * 8);
                acc[0][it] = mfma16(af[0], bp, acc[0][it]);
                acc[1][it] = mfma16(af[1], bp, acc[1][it]);
            }
        }
    }

    const float inv = 1.0f / (float)N_;
    const bool wnext = (layer < L_ - 1);
#pragma unroll
    for (int ns = 0; ns < 2; ns++)
#pragma unroll
        for (int it = 0; it < 8; it++) {
            const int i = i0 + it * 16 + l16;           // < 256
            const int nbase = n0w + ns * 16 + quad * 4; // < 1024
            bf16x4 zpk;
#pragma unroll
            for (int r = 0; r < 4; r++) {
                int n = nbase + r;
                size_t zi = ((size_t)b * NP1 + n) * DP1 + i;
                float v = Z[zi] + acc[ns][it][r] * inv;
                Z[zi] = v;
                zpk[r] = (bf16)v;
                if (wnext) Zb[((size_t)b * N_ + n) * D_ + i] = (bf16)v;
            }
            if (wnext)
                *(bf16x4*)(&ZbT[((size_t)b * DP1 + i) * MT + nbase]) = zpk;
        }
    // label column i = 256 (only i-half 0 blocks)
    if (ih == 0 && tid < 128) {
        int n = bx * 128 + tid;
        float s = 0.f;
#pragma unroll
        for (int h = 0; h < H_; h++)
            s += (float)Tlab[(size_t)(b * H_ + h) * TR_ + n];
        size_t zi = ((size_t)b * NP1 + n) * DP1 + D_;
        float v = Z[zi] + s * inv;
        Z[zi] = v;
        if (wnext) ZbT[((size_t)b * DP1 + D_) * MT + n] = (bf16)v;
    }
}

// ---------------------------------------------------------------------------
extern "C" void kernel_launch(void* const* d_in, const int* in_sizes, int n_in,
                              void* d_out, int out_size, void* d_ws, size_t ws_size,
                              hipStream_t stream) {
    const float* Zin = (const float*)d_in[0];
    const float* ap  = (const float*)d_in[1];
    float* Z = (float*)d_out;

    char* ws = (char*)d_ws;
    const size_t sz_Zb  = (size_t)B_ * N_ * D_ * sizeof(bf16);          // 33.6 MB
    const size_t sz_ZbT = (size_t)B_ * DP1 * MT * sizeof(bf16);         // 33.7 MB
    const size_t sz_T   = (size_t)B_ * H_ * TR_ * D_ * sizeof(bf16);    // 134.2 MB
    const size_t sz_Tl  = (size_t)B_ * H_ * TR_ * sizeof(bf16);         // 0.5 MB
    const size_t sz_P   = (size_t)L_ * H_ * D_ * D_ * sizeof(bf16);     // 2 MB
    bf16* Zb  = (bf16*)ws;
    bf16* ZbT = (bf16*)(ws + sz_Zb);
    bf16* Tb  = (bf16*)(ws + sz_Zb + sz_ZbT);
    bf16* Tl  = (bf16*)(ws + sz_Zb + sz_ZbT + sz_T);
    bf16* Pb  = (bf16*)(ws + sz_Zb + sz_ZbT + sz_T + sz_Tl);
    bf16* Qt  = (bf16*)(ws + sz_Zb + sz_ZbT + sz_T + sz_Tl + sz_P);

    hipMemcpyAsync(Z, Zin, (size_t)B_ * NP1 * DP1 * sizeof(float),
                   hipMemcpyDeviceToDevice, stream);

    k_prep_pq<<<dim3((L_ * H_ * D_ * D_) / 256), 256, 0, stream>>>(ap, Pb, Qt);
    k_zbt<<<dim3(N_ / 64, 5, B_), 256, 0, stream>>>(Z, Zb, ZbT);   // layer 0 only

    for (int l = 0; l < L_; l++) {
        k_attn<<<dim3(256), 512, 0, stream>>>(Zb, ZbT, Qt, Pb, Z, Tb, Tl, l);
        k_post<<<dim3(1024), 256, 0, stream>>>(Tb, Tl, Pb, Z, Zb, ZbT, l);
    }
}

// Round 9
// 3199.011 us; speedup vs baseline: 5.7302x; 1.0397x over previous
//
#include <hip/hip_runtime.h>
#include <cstdint>
#include <cstddef>

#define B_    64
#define NP1   1025
#define N_    1024
#define D_    256
#define DP1   257
#define L_    4
#define H_    4
#define MT    1024   // ZbT row length (m dim); m=1024 (masked key) excluded
#define NCHE  32     // 32 chunks x 32 m = 1024
#define IPAD  272
#define TR_   1024   // T rows per (b,h): n=0..1023 (row 1024 handled in-kernel tail)

typedef __bf16 bf16;
typedef bf16 bf16x4 __attribute__((ext_vector_type(4)));
typedef bf16 bf16x8 __attribute__((ext_vector_type(8)));
typedef float f32x4 __attribute__((ext_vector_type(4)));

__device__ __forceinline__ f32x4 mfma16(bf16x8 a, bf16x8 b, f32x4 c) {
    return __builtin_amdgcn_mfma_f32_16x16x32_bf16(a, b, c, 0, 0, 0);
}

__device__ __forceinline__ void async16(const void* g, void* l) {
    __builtin_amdgcn_global_load_lds(
        (const __attribute__((address_space(1))) void*)g,
        (__attribute__((address_space(3))) void*)l, 16, 0, 0);
}

// ---------------------------------------------------------------------------
__global__ void k_prep_pq(const float* __restrict__ ap,
                          bf16* __restrict__ Pb, bf16* __restrict__ Qt) {
    int idx = blockIdx.x * 256 + threadIdx.x;   // L*H*D*D = 1048576
    int j  = idx & 255;
    int i  = (idx >> 8) & 255;
    int lh = idx >> 16;
    const float* base = ap + (size_t)lh * 2 * D_ * D_;
    float p = base[i * D_ + j];
    float q = base[D_ * D_ + i * D_ + j];
    Pb[((size_t)lh * D_ + i) * D_ + j] = (bf16)p;
    Qt[((size_t)lh * D_ + j) * D_ + i] = (bf16)q;   // Qt[j][i] = Q[i][j]
}

// ---------------------------------------------------------------------------
// Per-layer staging: Zb[b][m][j] (j<256) and ZbT[b][j][m] (j<257), m<1024.
// Runs after each fused k_attn completes Z(l+1); doubles as the L2 warm-up
// for the next k_attn's staging (round-5 behavior).
// ---------------------------------------------------------------------------
__global__ __launch_bounds__(256) void k_zbt(const float* __restrict__ Z,
                                             bf16* __restrict__ Zb,
                                             bf16* __restrict__ ZbT) {
    __shared__ float t[64][65];
    int m0 = blockIdx.x * 64, j0 = blockIdx.y * 64, b = blockIdx.z;
    int c = threadIdx.x & 63, r0 = threadIdx.x >> 6;
#pragma unroll
    for (int s = 0; s < 16; s++) {
        int r = s * 4 + r0;
        int j = j0 + c;
        float v = (j < DP1) ? Z[((size_t)b * NP1 + m0 + r) * DP1 + j] : 0.f;
        t[r][c] = v;
        if (j < D_) Zb[((size_t)b * N_ + m0 + r) * D_ + j] = (bf16)v;
    }
    __syncthreads();
#pragma unroll
    for (int s = 0; s < 16; s++) {
        int rr = s * 4 + r0;
        int j = j0 + rr;
        if (j < DP1)
            ZbT[((size_t)b * DP1 + j) * MT + m0 + c] = (bf16)t[c][rr];
    }
}

// ---------------------------------------------------------------------------
// Fully fused layer kernel, 8-wave blocks (round-5 verified main structure):
// counted-vmcnt raw-barrier pipeline + serpentine head passes producing T,
// THEN a fused post phase: Z[n,i] += (1/N) sum_h T_h[n,:].P_h[i,:] — T rows
// are block-local (just written, L2/store-hot), so no global barrier needed.
// Zb/ZbT are READ-ONLY here (emission moved back to per-layer k_zbt), which
// removes all WAR races. bx==0 blocks also run the n=1024 query-row tail.
// Grid = exactly 256 blocks (one round), XCD-swizzled.
// ---------------------------------------------------------------------------
__global__ __launch_bounds__(512, 1) void k_attn(const bf16* __restrict__ Zb,
                                                 const bf16* __restrict__ ZbT,
                                                 const bf16* __restrict__ Qt,
                                                 const bf16* __restrict__ Pb,
                                                 float* __restrict__ Z,
                                                 bf16* __restrict__ T,
                                                 bf16* __restrict__ Tlab,
                                                 int layer) {
    __shared__ bf16 zbS[2][32][256];   // XOR-swizzled: f(r) = r&7
    __shared__ bf16 ztS[2][IPAD][32];  // f(r) = (r>>1)&3
    __shared__ bf16 sl[8][32][40];     // per-wave roundtrip scratch

    const int tid  = threadIdx.x;
    const int id   = blockIdx.x;
    const int wave = tid >> 6, lane = tid & 63;
    const int quad = lane >> 4, l16 = lane & 15;

    // bijective XCD mapping: 32 blocks per XCD = 8 b x 4 n-blocks
    const int xcd = id & 7, u = id >> 3;
    const int b   = xcd + 8 * (u & 7);
    const int bx  = u >> 3;             // 0..3
    const int n0w = bx * 256 + wave * 32;

    const bf16* Zbb  = Zb  + (size_t)b * N_ * D_;
    const bf16* ZbTb = ZbT + (size_t)b * DP1 * MT;

    const int zrow  = wave * 2 + (lane >> 5);          // 0..15
    const int zscol = ((lane & 31) ^ (zrow & 7)) * 8;
    const int krow  = wave * 16 + (lane >> 2);         // 0..127
    const int kscol = ((lane & 3) ^ ((lane >> 3) & 3)) * 8;
    const int xs    = l16 & 7;
    const int kf    = (l16 >> 1) & 3;

    auto stage = [&](int mc_, int p_) {
        int m0 = mc_ * 32;
        const bf16* zsrc = Zbb + (size_t)(m0 + zrow) * D_ + zscol;
#pragma unroll
        for (int t = 0; t < 2; t++)
            async16(zsrc + (size_t)t * 16 * D_, &zbS[p_][t * 16 + wave * 2][0]);
        const bf16* ksrc = ZbTb + (size_t)krow * MT + m0 + kscol;
#pragma unroll
        for (int t = 0; t < 2; t++)
            async16(ksrc + (size_t)t * 128 * MT, &ztS[p_][t * 128 + wave * 16][0]);
        if (wave == 0)
            async16(ksrc + (size_t)256 * MT, &ztS[p_][256][0]);
    };

    int p = 0;   // current LDS buffer parity (tracked across heads for reuse)

    for (int h = 0; h < H_; h++) {
        const bf16* Qth = Qt + (size_t)(layer * H_ + h) * D_ * D_;

        if (h == 0) stage(0, 0);   // overlap first-chunk fill with ZQ phase

        f32x4 acc[2][17];
#pragma unroll
        for (int ns = 0; ns < 2; ns++)
#pragma unroll
            for (int it = 0; it < 17; it++) acc[ns][it] = (f32x4){0.f, 0.f, 0.f, 0.f};

        // ---- phase 1: ZQ^T -> zqa frags (b64-packed roundtrip) ----
        bf16x8 zqa[2][8];
#pragma unroll 2
        for (int jc = 0; jc < 8; jc++) {
            f32x4 c00 = (f32x4){0.f,0.f,0.f,0.f}, c01 = c00, c10 = c00, c11 = c00;
#pragma unroll
            for (int kc = 0; kc < 8; kc++) {
                const bf16* qb = Qth + (size_t)(jc * 32 + l16) * D_ + kc * 32 + quad * 8;
                const bf16* az = Zbb + (size_t)(n0w + l16) * D_ + kc * 32 + quad * 8;
                bf16x8 q0 = *(const bf16x8*)(qb);
                bf16x8 q1 = *(const bf16x8*)(qb + 16 * D_);
                bf16x8 a0 = *(const bf16x8*)(az);
                bf16x8 a1 = *(const bf16x8*)(az + 16 * D_);
                c00 = mfma16(q0, a0, c00);
                c01 = mfma16(q0, a1, c01);
                c10 = mfma16(q1, a0, c10);
                c11 = mfma16(q1, a1, c11);
            }
            f32x4 cv[2][2] = {{c00, c01}, {c10, c11}};
#pragma unroll
            for (int jt = 0; jt < 2; jt++)
#pragma unroll
                for (int ns = 0; ns < 2; ns++) {
                    bf16x4 pk;
#pragma unroll
                    for (int r = 0; r < 4; r++) pk[r] = (bf16)cv[jt][ns][r];
                    *(bf16x4*)(&sl[wave][ns * 16 + l16][jt * 16 + quad * 4]) = pk;
                }
#pragma unroll
            for (int ns = 0; ns < 2; ns++)
                zqa[ns][jc] = *(const bf16x8*)(&sl[wave][ns * 16 + l16][quad * 8]);
        }

        if (h == 0) {
            // chunk 0 must be resident before the pipeline starts
            asm volatile("s_waitcnt vmcnt(0)" ::: "memory");
            __builtin_amdgcn_s_barrier();
            __builtin_amdgcn_sched_barrier(0);
        }
        // h>0: current buffer p already holds this head's first chunk
        // (serpentine reuse: head h starts where head h-1 ended).

        for (int cc = 0; cc < NCHE; cc++) {
            const bool haveNext = (cc + 1 < NCHE);
            if (haveNext) {
                int mcn = (h & 1) ? (NCHE - 2 - cc) : (cc + 1);
                stage(mcn, p ^ 1);
                // wait own current-chunk loads; leave next-chunk (4/5) in flight
                if (wave == 0) asm volatile("s_waitcnt vmcnt(5)" ::: "memory");
                else           asm volatile("s_waitcnt vmcnt(4)" ::: "memory");
            } else {
                asm volatile("s_waitcnt vmcnt(0)" ::: "memory");
            }
            __builtin_amdgcn_s_barrier();        // all waves' chunk-cc loads landed
            __builtin_amdgcn_sched_barrier(0);

            // ---- S^T = relu(Zb_chunk . ZQ^T), b64-packed roundtrip ----
#pragma unroll
            for (int mt = 0; mt < 2; mt++) {
                f32x4 st0 = (f32x4){0.f,0.f,0.f,0.f}, st1 = st0;
                const bf16* zr = &zbS[p][mt * 16 + l16][0];
                __builtin_amdgcn_s_setprio(1);
#pragma unroll
                for (int kc = 0; kc < 8; kc++) {
                    bf16x8 az = *(const bf16x8*)(zr + (((kc * 4 + quad) ^ xs) * 8));
                    st0 = mfma16(az, zqa[0][kc], st0);
                    st1 = mfma16(az, zqa[1][kc], st1);
                }
                __builtin_amdgcn_s_setprio(0);
                bf16x4 p0, p1;
#pragma unroll
                for (int r = 0; r < 4; r++) {
                    p0[r] = (bf16)(st0[r] > 0.f ? st0[r] : 0.f);
                    p1[r] = (bf16)(st1[r] > 0.f ? st1[r] : 0.f);
                }
                *(bf16x4*)(&sl[wave][l16][mt * 16 + quad * 4])      = p0;
                *(bf16x4*)(&sl[wave][16 + l16][mt * 16 + quad * 4]) = p1;
            }
            bf16x8 sfrag[2];
#pragma unroll
            for (int ns = 0; ns < 2; ns++)
                sfrag[ns] = *(const bf16x8*)(&sl[wave][ns * 16 + l16][quad * 8]);

            // ---- acc(T) += S . ZbT_chunk^T ----
            __builtin_amdgcn_s_setprio(1);
#pragma unroll
            for (int it = 0; it < 17; it++) {
                const bf16* kr = &ztS[p][it * 16 + l16][0];
                bf16x8 bk = *(const bf16x8*)(kr + ((quad ^ kf) * 8));
                acc[0][it] = mfma16(sfrag[0], bk, acc[0][it]);
                acc[1][it] = mfma16(sfrag[1], bk, acc[1][it]);
            }
            __builtin_amdgcn_s_setprio(0);

            __builtin_amdgcn_sched_barrier(0);
            __builtin_amdgcn_s_barrier();        // all waves done reading buf p
            if (haveNext) p ^= 1;
        }

        // ---- per-head epilogue: write T (bf16); j=256 goes to Tlab ----
        bf16* Th  = T    + (size_t)(b * H_ + h) * TR_ * D_;
        bf16* Tlh = Tlab + (size_t)(b * H_ + h) * TR_;
#pragma unroll
        for (int ns = 0; ns < 2; ns++)
#pragma unroll
            for (int it = 0; it < 17; it++)
#pragma unroll
                for (int r = 0; r < 4; r++) {
                    int n = n0w + ns * 16 + quad * 4 + r;   // < 1024
                    float v = acc[ns][it][r];
                    if (it < 16)
                        Th[(size_t)n * D_ + it * 16 + l16] = (bf16)v;
                    else if (l16 == 0)
                        Tlh[n] = (bf16)v;
                }
    }

    // ======== fused post phase: Z += (1/N) sum_h T_h . P_h^T ========
    // T/Tlab rows for this block's n-range were written by this block only;
    // __syncthreads drains the stores (vmcnt 0) and syncs Tlab across waves.
    __syncthreads();
    {
        f32x4 acc2[2][16];
#pragma unroll
        for (int ns = 0; ns < 2; ns++)
#pragma unroll
            for (int it = 0; it < 16; it++) acc2[ns][it] = (f32x4){0.f, 0.f, 0.f, 0.f};

        for (int h = 0; h < H_; h++) {
            const bf16* Th = T  + (size_t)(b * H_ + h) * TR_ * D_;
            const bf16* Ph = Pb + (size_t)(layer * H_ + h) * D_ * D_;
#pragma unroll 2
            for (int kc = 0; kc < 8; kc++) {
                bf16x8 af[2];
#pragma unroll
                for (int ns = 0; ns < 2; ns++) {
                    int row = n0w + ns * 16 + l16;   // < 1024, block-local T rows
                    af[ns] = *(const bf16x8*)(Th + (size_t)row * D_ + kc * 32 + quad * 8);
                }
#pragma unroll
                for (int it = 0; it < 16; it++) {
                    bf16x8 bp = *(const bf16x8*)(Ph + (size_t)(it * 16 + l16) * D_ + kc * 32 + quad * 8);
                    acc2[0][it] = mfma16(af[0], bp, acc2[0][it]);
                    acc2[1][it] = mfma16(af[1], bp, acc2[1][it]);
                }
            }
        }

        const float inv = 1.0f / (float)N_;
#pragma unroll
        for (int ns = 0; ns < 2; ns++)
#pragma unroll
            for (int it = 0; it < 16; it++) {
                const int i = it * 16 + l16;                // < 256
                const int nbase = n0w + ns * 16 + quad * 4; // < 1024
#pragma unroll
                for (int r = 0; r < 4; r++) {
                    size_t zi = ((size_t)b * NP1 + nbase + r) * DP1 + i;
                    Z[zi] += acc2[ns][it][r] * inv;
                }
            }
        // label column i = 256 for this block's 256 rows
        if (tid < 256) {
            int n = bx * 256 + tid;
            float s = 0.f;
#pragma unroll
            for (int h = 0; h < H_; h++)
                s += (float)Tlab[(size_t)(b * H_ + h) * TR_ + n];
            Z[((size_t)b * NP1 + n) * DP1 + D_] += s * inv;
        }
    }

    // ---- n=1024 query row: bx==0 block of each b, all 4 heads fused ----
    // Reads Zb/ZbT (read-only this layer) and Z row 1024 (untouched by posts).
    if (bx == 0) {
        __syncthreads();   // all waves past post phase; zbS free for reuse
        float* lz1 = (float*)&zbS[0][0][0];   // 256 f32
        float* lzq = lz1 + 256;               // [4][256]
        float* lsS = lzq + 1024;              // [4][1024]
        float* lT  = lsS + 4096;              // [4][257]   (total 25.6 KB < zbS)
        if (tid < 256) lz1[tid] = Z[((size_t)b * NP1 + N_) * DP1 + tid];
        __syncthreads();
        {   // zq[h][j] = sum_i z1[i] Q_h[i][j]; threads 0..255 do h=0,2; 256..511 h=1,3
            int j = tid & 255, hh = tid >> 8;
            for (int h2 = hh; h2 < H_; h2 += 2) {
                const bf16* qr = Qt + ((size_t)(layer * H_ + h2) * D_ + j) * D_;
                float a = 0.f;
                for (int i8 = 0; i8 < 32; i8++) {
                    bf16x8 q = *(const bf16x8*)(qr + i8 * 8);
#pragma unroll
                    for (int k = 0; k < 8; k++) a += lz1[i8 * 8 + k] * (float)q[k];
                }
                lzq[h2 * 256 + j] = a;
            }
        }
        __syncthreads();
        for (int m = tid; m < N_; m += 512) {   // one Zb sweep, 4 heads
            const bf16* zr = Zbb + (size_t)m * D_;
            float a0 = 0.f, a1 = 0.f, a2 = 0.f, a3 = 0.f;
            for (int j8 = 0; j8 < 32; j8++) {
                bf16x8 z8 = *(const bf16x8*)(zr + j8 * 8);
#pragma unroll
                for (int k = 0; k < 8; k++) {
                    float zv = (float)z8[k];
                    int j = j8 * 8 + k;
                    a0 += lzq[j] * zv;
                    a1 += lzq[256 + j] * zv;
                    a2 += lzq[512 + j] * zv;
                    a3 += lzq[768 + j] * zv;
                }
            }
            lsS[m]        = a0 > 0.f ? a0 : 0.f;
            lsS[1024 + m] = a1 > 0.f ? a1 : 0.f;
            lsS[2048 + m] = a2 > 0.f ? a2 : 0.f;
            lsS[3072 + m] = a3 > 0.f ? a3 : 0.f;
        }
        __syncthreads();
        if (tid < DP1) {   // one ZbT sweep, 4 heads: lT[h][j=tid]
            const bf16* tr2 = ZbTb + (size_t)tid * MT;
            float t0 = 0.f, t1 = 0.f, t2 = 0.f, t3 = 0.f;
            for (int m8 = 0; m8 < 128; m8++) {
                bf16x8 t8 = *(const bf16x8*)(tr2 + m8 * 8);
#pragma unroll
                for (int k = 0; k < 8; k++) {
                    float zv = (float)t8[k];
                    int m = m8 * 8 + k;
                    t0 += lsS[m] * zv;
                    t1 += lsS[1024 + m] * zv;
                    t2 += lsS[2048 + m] * zv;
                    t3 += lsS[3072 + m] * zv;
                }
            }
            lT[tid] = t0; lT[257 + tid] = t1; lT[514 + tid] = t2; lT[771 + tid] = t3;
        }
        __syncthreads();
        const float inv = 1.0f / (float)N_;
        if (tid < 256) {   // P contraction, all 4 heads
            float out = 0.f;
            for (int h2 = 0; h2 < H_; h2++) {
                const bf16* pr = Pb + ((size_t)(layer * H_ + h2) * D_ + tid) * D_;
                for (int j8 = 0; j8 < 32; j8++) {
                    bf16x8 p8 = *(const bf16x8*)(pr + j8 * 8);
#pragma unroll
                    for (int k = 0; k < 8; k++)
                        out += lT[h2 * 257 + j8 * 8 + k] * (float)p8[k];
                }
            }
            Z[((size_t)b * NP1 + N_) * DP1 + tid] += out * inv;
        } else if (tid == 256) {
            float lab = lT[256] + lT[513] + lT[770] + lT[1027];
            Z[((size_t)b * NP1 + N_) * DP1 + D_] += lab * inv;
        }
    }
}

// ---------------------------------------------------------------------------
extern "C" void kernel_launch(void* const* d_in, const int* in_sizes, int n_in,
                              void* d_out, int out_size, void* d_ws, size_t ws_size,
                              hipStream_t stream) {
    const float* Zin = (const float*)d_in[0];
    const float* ap  = (const float*)d_in[1];
    float* Z = (float*)d_out;

    char* ws = (char*)d_ws;
    const size_t sz_Zb  = (size_t)B_ * N_ * D_ * sizeof(bf16);          // 33.6 MB
    const size_t sz_ZbT = (size_t)B_ * DP1 * MT * sizeof(bf16);         // 33.7 MB
    const size_t sz_T   = (size_t)B_ * H_ * TR_ * D_ * sizeof(bf16);    // 134.2 MB
    const size_t sz_Tl  = (size_t)B_ * H_ * TR_ * sizeof(bf16);         // 0.5 MB
    const size_t sz_P   = (size_t)L_ * H_ * D_ * D_ * sizeof(bf16);     // 2 MB
    bf16* Zb  = (bf16*)ws;
    bf16* ZbT = (bf16*)(ws + sz_Zb);
    bf16* Tb  = (bf16*)(ws + sz_Zb + sz_ZbT);
    bf16* Tl  = (bf16*)(ws + sz_Zb + sz_ZbT + sz_T);
    bf16* Pb  = (bf16*)(ws + sz_Zb + sz_ZbT + sz_T + sz_Tl);
    bf16* Qt  = (bf16*)(ws + sz_Zb + sz_ZbT + sz_T + sz_Tl + sz_P);

    hipMemcpyAsync(Z, Zin, (size_t)B_ * NP1 * DP1 * sizeof(float),
                   hipMemcpyDeviceToDevice, stream);

    k_prep_pq<<<dim3((L_ * H_ * D_ * D_) / 256), 256, 0, stream>>>(ap, Pb, Qt);
    k_zbt<<<dim3(N_ / 64, 5, B_), 256, 0, stream>>>(Z, Zb, ZbT);   // layer 0

    for (int l = 0; l < L_; l++) {
        k_attn<<<dim3(256), 512, 0, stream>>>(Zb, ZbT, Qt, Pb, Z, Tb, Tl, l);
        if (l < L_ - 1)
            k_zbt<<<dim3(N_ / 64, 5, B_), 256, 0, stream>>>(Z, Zb, ZbT);
    }
}